// Round 4
// baseline (316.147 us; speedup 1.0000x reference)
//
#include <hip/hip_runtime.h>
#include <cstdint>
#include <cstddef>

#define EPSV 1e-5f
constexpr int B_ = 8;
constexpr int C_ = 512;
constexpr int N_ = 2048;

typedef _Float16 f16x8 __attribute__((ext_vector_type(8)));
typedef float    f32x4 __attribute__((ext_vector_type(4)));

__device__ __forceinline__ unsigned short f16b(float f) {
    _Float16 h = (_Float16)f;
    return __builtin_bit_cast(unsigned short, h);
}

__device__ __forceinline__ void gload_lds16(const void* g, void* l) {
    __builtin_amdgcn_global_load_lds(
        (const __attribute__((address_space(1))) void*)g,
        (__attribute__((address_space(3))) void*)l, 16, 0, 0);
}

// ---------------------------------------------------------------------------
// x (B,C,N) fp32 -> xT (B,N,C) fp16 (transposed so all GEMMs are K-contig)
// ---------------------------------------------------------------------------
__global__ __launch_bounds__(256) void split_x_kernel(
    const float* __restrict__ x, unsigned short* __restrict__ xh)
{
    __shared__ float T[64][65];
    const int b = blockIdx.z, c0 = blockIdx.y * 64, n0 = blockIdx.x * 64;
    const float* xb = x + ((size_t)b * C_ + c0) * N_ + n0;
    const int tid = threadIdx.x;
    const int lr = tid >> 4;
    const int lcn = (tid & 15) * 4;
#pragma unroll
    for (int it = 0; it < 4; ++it) {
        float4 v = *(const float4*)&xb[(size_t)(lr + 16 * it) * N_ + lcn];
        T[lr + 16 * it][lcn + 0] = v.x;
        T[lr + 16 * it][lcn + 1] = v.y;
        T[lr + 16 * it][lcn + 2] = v.z;
        T[lr + 16 * it][lcn + 3] = v.w;
    }
    __syncthreads();
    const int n = tid >> 2, cb = (tid & 3) * 16;
    alignas(16) unsigned short h[16];
#pragma unroll
    for (int i = 0; i < 16; ++i)
        h[i] = f16b(T[cb + i][n]);
    const size_t o = ((size_t)b * N_ + n0 + n) * C_ + c0 + cb;
    *(uint4*)&xh[o]     = *(uint4*)&h[0];
    *(uint4*)&xh[o + 8] = *(uint4*)&h[8];
}

// ---------------------------------------------------------------------------
// W (512x512) fp32 -> fp16 (layout unchanged; K=c already contig)
// ---------------------------------------------------------------------------
__global__ __launch_bounds__(256) void split_w_kernel(
    const float* __restrict__ W, unsigned short* __restrict__ wh)
{
    const int i = (blockIdx.x * 256 + threadIdx.x) * 4;
    float4 v = *(const float4*)&W[i];
    alignas(8) unsigned short h[4];
    h[0] = f16b(v.x); h[1] = f16b(v.y); h[2] = f16b(v.z); h[3] = f16b(v.w);
    *(ushort4*)&wh[i] = *(ushort4*)&h[0];
}

// ---------------------------------------------------------------------------
// MFMA GEMM (fp16 in, fp32 acc): C = A * B^T.  m97 structure, 128x128 tile.
// EPI: 0=QK (fp32 w[m*N+n]), 2=PROJT (BN by m, fp16 at [n*M+m]),
//      3=PROJV (BN by n, fp16 at [n*M+m])
// ---------------------------------------------------------------------------
constexpr int EPI_QK = 0, EPI_PROJT = 2, EPI_PROJV = 3;

template <int EPI>
__global__ __launch_bounds__(256) void gemm_mfma(
    const unsigned short* __restrict__ Ah, const unsigned short* __restrict__ Bh,
    int M, int N, int K, int lda, int ldb,
    long strideA, long strideB, long strideC,
    void* __restrict__ C0,
    const float* __restrict__ g, const float* __restrict__ bt,
    const float* __restrict__ mu, const float* __restrict__ var)
{
    __shared__ char smem[16384];   // A: [0,8K), B: [8K,16K)

    const int bz = blockIdx.z;
    const unsigned short* Ahb = Ah + (size_t)bz * strideA;
    const unsigned short* Bhb = Bh + (size_t)bz * strideB;

    const int n0 = blockIdx.x * 128;
    const int m0 = blockIdx.y * 128;

    const int tid = threadIdx.x;
    const int lane = tid & 63;
    const int wv = tid >> 6;
    const int wr = wv >> 1, wc = wv & 1;
    const int l4 = lane >> 4, l15 = lane & 15;
    const int srow = lane >> 2, scol8 = (lane & 3) * 8;

    f32x4 acc[4][4] = {};

    for (int k0 = 0; k0 < K; k0 += 32) {
#pragma unroll
        for (int cc = 0; cc < 2; ++cc) {
            const int c = wv * 2 + cc;
            const size_t aoff = (size_t)(m0 + c * 16 + srow) * lda + k0 + scol8;
            const size_t boff = (size_t)(n0 + c * 16 + srow) * ldb + k0 + scol8;
            gload_lds16(Ahb + aoff, smem + c * 1024);
            gload_lds16(Bhb + boff, smem + 8192 + c * 1024);
        }
        __syncthreads();

        f16x8 ah[4], bh[4];
#pragma unroll
        for (int f = 0; f < 4; ++f) {
            const int arow = wr * 64 + f * 16 + l15;
            const int brow = wc * 64 + f * 16 + l15;
            ah[f] = *(const f16x8*)(smem + arow * 64 + l4 * 16);
            bh[f] = *(const f16x8*)(smem + 8192 + brow * 64 + l4 * 16);
        }
#pragma unroll
        for (int fm = 0; fm < 4; ++fm)
#pragma unroll
            for (int fn = 0; fn < 4; ++fn)
                acc[fm][fn] = __builtin_amdgcn_mfma_f32_16x16x32_f16(
                    ah[fm], bh[fn], acc[fm][fn], 0, 0, 0);
        __syncthreads();
    }

#pragma unroll
    for (int fm = 0; fm < 4; ++fm) {
#pragma unroll
        for (int fn = 0; fn < 4; ++fn) {
            const int m = m0 + wr * 64 + fm * 16 + l4 * 4;
            const int n = n0 + wc * 64 + fn * 16 + l15;
            if constexpr (EPI == EPI_QK) {
                float* Cb = (float*)C0 + (size_t)bz * strideC;
#pragma unroll
                for (int r = 0; r < 4; ++r)
                    Cb[(size_t)(m + r) * N + n] = acc[fm][fn][r];
            } else if constexpr (EPI == EPI_PROJT) {
                unsigned short* H = (unsigned short*)C0 + (size_t)bz * strideC;
                alignas(8) unsigned short h4[4];
#pragma unroll
                for (int r = 0; r < 4; ++r) {
                    const int o = m + r;
                    const float sc = g[o] * rsqrtf(var[o] + EPSV);
                    const float sh = bt[o] - mu[o] * sc;
                    h4[r] = f16b(acc[fm][fn][r] * sc + sh);
                }
                *(ushort4*)&H[(size_t)n * M + m] = *(ushort4*)&h4[0];
            } else {  // EPI_PROJV: BN param by col n
                unsigned short* H = (unsigned short*)C0 + (size_t)bz * strideC;
                const float sc = g[n] * rsqrtf(var[n] + EPSV);
                const float sh = bt[n] - mu[n] * sc;
                alignas(8) unsigned short h4[4];
#pragma unroll
                for (int r = 0; r < 4; ++r)
                    h4[r] = f16b(acc[fm][fn][r] * sc + sh);
                *(ushort4*)&H[(size_t)n * M + m] = *(ushort4*)&h4[0];
            }
        }
    }
}

// ---------------------------------------------------------------------------
// Fused online-softmax + PV.  Computes out[b,d,i] = sum_j softmax(w[b,i,:])[j]
// * v[b,d,j] as O^T = v * P^T via MFMA, streaming w fp32 from L3/HBM.
//
// Layout trick: mfma_16x16x32 A/B-fragment is lane={n or m}=l&15,
// k=(l>>4)*8+e.  So lane (l15,l4) loads w[i=nt*16+l15][j0+l4*8..+8] (8 consec
// fp32) -> row stats need only shfl_xor(16/32); exp() in-register -> f16x8 B;
// v[d=mt*16+l15][j0+l4*8..] f16x8 -> A.  C-frag col=l15=i matches the stats
// lane, so m/l/div never cross lanes.  8 waves split D (64 each); no LDS,
// no barriers.  Register-double-buffered prefetch (named bufs, rule #20).
// ---------------------------------------------------------------------------
struct PvBuf {
    float4 w0[4], w1[4];   // per nt: 8 fp32 of w
    uint4  vv[4];          // per mt: 8 fp16 of v
};

__global__ __launch_bounds__(512) void fused_softmax_pv(
    const float* __restrict__ w, const unsigned short* __restrict__ v,
    float* __restrict__ out)
{
    const int b  = blockIdx.y;
    const int i0 = blockIdx.x * 64;
    const float* wb = w + (size_t)b * N_ * N_;
    const unsigned short* vb = v + (size_t)b * C_ * N_;   // (d, j) j-contig
    float* ob = out + (size_t)b * C_ * N_;

    const int tid  = threadIdx.x;
    const int lane = tid & 63;
    const int wv   = tid >> 6;            // 0..7, D-slice owner
    const int l4   = lane >> 4, l15 = lane & 15;
    const int dOff = wv * 64;

    const float* wrow[4];
#pragma unroll
    for (int nt = 0; nt < 4; ++nt)
        wrow[nt] = wb + (size_t)(i0 + nt * 16 + l15) * N_ + l4 * 8;
    const unsigned short* vrow[4];
#pragma unroll
    for (int mt = 0; mt < 4; ++mt)
        vrow[mt] = vb + (size_t)(dOff + mt * 16 + l15) * N_ + l4 * 8;

    f32x4 acc[4][4] = {};                 // [mt][nt]
    float m_reg[4], l_reg[4];
#pragma unroll
    for (int t = 0; t < 4; ++t) { m_reg[t] = -3.0e38f; l_reg[t] = 0.f; }

#define PV_LOAD(buf, js)                                                     \
    {                                                                        \
        const int j32 = (js) * 32;                                           \
        _Pragma("unroll")                                                    \
        for (int nt = 0; nt < 4; ++nt) {                                     \
            buf.w0[nt] = *(const float4*)(wrow[nt] + j32);                   \
            buf.w1[nt] = *(const float4*)(wrow[nt] + j32 + 4);               \
        }                                                                    \
        _Pragma("unroll")                                                    \
        for (int mt = 0; mt < 4; ++mt)                                       \
            buf.vv[mt] = *(const uint4*)(vrow[mt] + j32);                    \
    }

#define PV_PROC(buf)                                                         \
    {                                                                        \
        _Pragma("unroll")                                                    \
        for (int nt = 0; nt < 4; ++nt) {                                     \
            const float* wp0 = (const float*)&buf.w0[nt];                    \
            const float* wp1 = (const float*)&buf.w1[nt];                    \
            float mx = fmaxf(fmaxf(fmaxf(wp0[0], wp0[1]), fmaxf(wp0[2], wp0[3])), \
                             fmaxf(fmaxf(wp1[0], wp1[1]), fmaxf(wp1[2], wp1[3]))); \
            mx = fmaxf(mx, __shfl_xor(mx, 16));                              \
            mx = fmaxf(mx, __shfl_xor(mx, 32));                              \
            const float mnew = fmaxf(m_reg[nt], mx);                         \
            const float al = __expf(m_reg[nt] - mnew);                       \
            m_reg[nt] = mnew;                                                \
            float s = 0.f;                                                   \
            f16x8 pf;                                                        \
            _Pragma("unroll")                                                \
            for (int e = 0; e < 4; ++e) {                                    \
                float pe = __expf(wp0[e] - mnew);                            \
                s += pe; pf[e] = (_Float16)pe;                               \
            }                                                                \
            _Pragma("unroll")                                                \
            for (int e = 0; e < 4; ++e) {                                    \
                float pe = __expf(wp1[e] - mnew);                            \
                s += pe; pf[4 + e] = (_Float16)pe;                           \
            }                                                                \
            l_reg[nt] = l_reg[nt] * al + s;                                  \
            _Pragma("unroll")                                                \
            for (int mt = 0; mt < 4; ++mt) {                                 \
                _Pragma("unroll")                                            \
                for (int r = 0; r < 4; ++r) acc[mt][nt][r] *= al;            \
                acc[mt][nt] = __builtin_amdgcn_mfma_f32_16x16x32_f16(        \
                    *(const f16x8*)&buf.vv[mt], pf, acc[mt][nt], 0, 0, 0);   \
            }                                                                \
        }                                                                    \
    }

    PvBuf bufA, bufB;
    PV_LOAD(bufA, 0);
    for (int js = 0; js < 64; js += 2) {
        PV_LOAD(bufB, js + 1);
        PV_PROC(bufA);
        const int jn = (js + 2 < 64) ? js + 2 : 63;
        PV_LOAD(bufA, jn);
        PV_PROC(bufB);
    }

    // final: divide by full-row l and store O^T
    float inv[4];
#pragma unroll
    for (int nt = 0; nt < 4; ++nt) {
        float s = l_reg[nt];
        s += __shfl_xor(s, 16);
        s += __shfl_xor(s, 32);
        inv[nt] = 1.0f / s;
    }
#pragma unroll
    for (int mt = 0; mt < 4; ++mt)
#pragma unroll
        for (int nt = 0; nt < 4; ++nt) {
            const int i = i0 + nt * 16 + l15;
#pragma unroll
            for (int r = 0; r < 4; ++r) {
                const int d = dOff + mt * 16 + l4 * 4 + r;
                ob[(size_t)d * N_ + i] = acc[mt][nt][r] * inv[nt];
            }
        }
#undef PV_LOAD
#undef PV_PROC
}

// ---------------------------------------------------------------------------
extern "C" void kernel_launch(void* const* d_in, const int* in_sizes, int n_in,
                              void* d_out, int out_size, void* d_ws, size_t ws_size,
                              hipStream_t stream)
{
    (void)in_sizes; (void)n_in; (void)out_size; (void)ws_size;
    const float* x  = (const float*)d_in[0];
    const float* Wq = (const float*)d_in[1];
    const float* gq = (const float*)d_in[2];
    const float* bq = (const float*)d_in[3];
    const float* mq = (const float*)d_in[4];
    const float* vq = (const float*)d_in[5];
    const float* Wk = (const float*)d_in[6];
    const float* gk = (const float*)d_in[7];
    const float* bk = (const float*)d_in[8];
    const float* mk = (const float*)d_in[9];
    const float* vk = (const float*)d_in[10];
    const float* Wv = (const float*)d_in[11];
    const float* gv = (const float*)d_in[12];
    const float* bv = (const float*)d_in[13];
    const float* mv = (const float*)d_in[14];
    const float* vv = (const float*)d_in[15];
    float* out = (float*)d_out;

    const size_t MiB = 1048576;
    char* ws = (char*)d_ws;
    unsigned short* Wqh = (unsigned short*)(ws + 0 * 524288);
    unsigned short* Wkh = (unsigned short*)(ws + 1 * 524288);
    unsigned short* Wvh = (unsigned short*)(ws + 2 * 524288);
    unsigned short* vbf = (unsigned short*)(ws + 2 * MiB);    // 16 MiB (C,N)
    unsigned short* qTh = (unsigned short*)(ws + 18 * MiB);   // 16 MiB (N,C)
    unsigned short* kTh = (unsigned short*)(ws + 34 * MiB);   // 16 MiB (N,C)
    unsigned short* xTh = (unsigned short*)(ws + 50 * MiB);   // 16 MiB (N,C)
    float* wbuf = (float*)(ws + 66 * MiB);                    // 128 MiB fp32

    const long BS = (long)N_ * C_;  // 1,048,576 elems per batch

    // --- fp16 conversions ---
    split_x_kernel<<<dim3(N_ / 64, C_ / 64, B_), 256, 0, stream>>>(x, xTh);
    split_w_kernel<<<dim3(256), 256, 0, stream>>>(Wq, Wqh);
    split_w_kernel<<<dim3(256), 256, 0, stream>>>(Wk, Wkh);
    split_w_kernel<<<dim3(256), 256, 0, stream>>>(Wv, Wvh);

    // --- projections ---
    gemm_mfma<EPI_PROJT><<<dim3(16, 4, B_), 256, 0, stream>>>(
        Wqh, xTh, 512, 2048, 512, 512, 512, 0, BS, BS, qTh, gq, bq, mq, vq);
    gemm_mfma<EPI_PROJT><<<dim3(16, 4, B_), 256, 0, stream>>>(
        Wkh, xTh, 512, 2048, 512, 512, 512, 0, BS, BS, kTh, gk, bk, mk, vk);
    gemm_mfma<EPI_PROJV><<<dim3(4, 16, B_), 256, 0, stream>>>(
        xTh, Wvh, 2048, 512, 512, 512, 512, BS, 0, BS, vbf, gv, bv, mv, vv);

    // --- logits: M=i, N=j (2048x2048), K=c(512); fp32 w ---
    gemm_mfma<EPI_QK><<<dim3(16, 16, B_), 256, 0, stream>>>(
        qTh, kTh, 2048, 2048, 512, 512, 512, BS, BS, (long)N_ * N_, wbuf,
        nullptr, nullptr, nullptr, nullptr);

    // --- fused online-softmax + PV ---
    fused_softmax_pv<<<dim3(N_ / 64, B_), 512, 0, stream>>>(wbuf, vbf, out);
}